// Round 3
// baseline (1778.551 us; speedup 1.0000x reference)
//
#include <hip/hip_runtime.h>

// HypergraphGuidedChebNet on MI355X.
// Pipeline per call:
//   1. zero counters  2. degrees (atomic histograms)  3. norms
//   4. scans -> CSR ptrs  5. fill CSR (atomic cursors)  6. init acc/T0
//   7. 10x [phaseA edge-gather, phaseB node-gather + Cheb recurrence + acc]
//   8. fp32 tiled GEMM (acc @ W^T + b, ReLU), BK=64 staging (34.8 KB LDS)
//
// NOTE (round 3 fix): harness passes integer inputs as int32 — hyperedge_index
// is const int* with layout [2, NNZ] row-major. Reading it as long long was an
// OOB read (12.8MB from a 6.4MB buffer) -> memory fault -> the r1/r2 aborts.
//
// Memory plan: prop-loop scratch lives in d_out (unused until GEMM):
//   d_out: [bufA 25.6MB][bufB 25.6MB][m_e 5.12MB][edge_node 3.2MB][node_edge 3.2MB]
//   d_ws:  [accv 25.6MB][small degree/CSR arrays ~1MB]

#define N_NODES 50000
#define N_EDGES 10000
#define NNZ     800000
#define F_IN    128
#define HID     512
#define F4      (F_IN / 4)   // 32 float4 per row

// ---------------------------------------------------------------- zero counters
__global__ void k_zero(float* __restrict__ d_v,
                       int* __restrict__ d_e_cnt,
                       int* __restrict__ n_cnt,
                       int* __restrict__ edge_cur,
                       int* __restrict__ node_cur) {
    int i = blockIdx.x * blockDim.x + threadIdx.x;
    if (i < N_NODES) { d_v[i] = 0.f; n_cnt[i] = 0; node_cur[i] = 0; }
    if (i < N_EDGES) { d_e_cnt[i] = 0; edge_cur[i] = 0; }
}

// ---------------------------------------------------------------- degrees
__global__ void k_degrees(const int* __restrict__ hidx,
                          const float* __restrict__ ew,
                          int* __restrict__ d_e_cnt,
                          int* __restrict__ n_cnt,
                          float* __restrict__ d_v) {
    int i = blockIdx.x * blockDim.x + threadIdx.x;
    if (i >= NNZ) return;
    int v = hidx[i];
    int e = hidx[NNZ + i];
    v = min(max(v, 0), N_NODES - 1);
    e = min(max(e, 0), N_EDGES - 1);
    atomicAdd(&d_e_cnt[e], 1);
    atomicAdd(&n_cnt[v], 1);
    atomicAdd(&d_v[v], ew[e]);
}

// ---------------------------------------------------------------- norms
__global__ void k_norms(const float* __restrict__ d_v,
                        const int* __restrict__ d_e_cnt,
                        const float* __restrict__ ew,
                        float* __restrict__ dv_is,
                        float* __restrict__ de_w) {
    int i = blockIdx.x * blockDim.x + threadIdx.x;
    if (i < N_NODES) {
        float d = d_v[i];
        dv_is[i] = (d > 0.f) ? rsqrtf(fmaxf(d, 1e-12f)) : 0.f;
    }
    if (i < N_EDGES) {
        int c = d_e_cnt[i];
        de_w[i] = ew[i] * ((c > 0) ? (1.f / (float)c) : 0.f);
    }
}

// ---------------------------------------------------------------- scan (exclusive, single block)
__global__ void k_scan(const int* __restrict__ counts, int n, int* __restrict__ ptr) {
    __shared__ int sd[1024];
    __shared__ int carry;
    if (threadIdx.x == 0) carry = 0;
    __syncthreads();
    for (int base = 0; base < n; base += 1024) {
        int i = base + (int)threadIdx.x;
        int val = (i < n) ? counts[i] : 0;
        sd[threadIdx.x] = val;
        __syncthreads();
        for (int off = 1; off < 1024; off <<= 1) {
            int t = (threadIdx.x >= (unsigned)off) ? sd[threadIdx.x - off] : 0;
            __syncthreads();
            sd[threadIdx.x] += t;
            __syncthreads();
        }
        if (i < n) ptr[i] = carry + sd[threadIdx.x] - val;  // exclusive
        __syncthreads();
        if (threadIdx.x == 1023) carry += sd[1023];
        __syncthreads();
    }
    if (threadIdx.x == 0) ptr[n] = carry;
}

// ---------------------------------------------------------------- CSR fill
__global__ void k_fill(const int* __restrict__ hidx,
                       const int* __restrict__ edge_ptr,
                       const int* __restrict__ node_ptr,
                       int* __restrict__ edge_cur,
                       int* __restrict__ node_cur,
                       int* __restrict__ edge_node,
                       int* __restrict__ node_edge) {
    int i = blockIdx.x * blockDim.x + threadIdx.x;
    if (i >= NNZ) return;
    int v = hidx[i];
    int e = hidx[NNZ + i];
    v = min(max(v, 0), N_NODES - 1);
    e = min(max(e, 0), N_EDGES - 1);
    int p = atomicAdd(&edge_cur[e], 1);
    edge_node[edge_ptr[e] + p] = v;
    int q = atomicAdd(&node_cur[v], 1);
    node_edge[node_ptr[v] + q] = e;
}

// ---------------------------------------------------------------- init: bufA = x (T0), acc = theta0 * x
__global__ void k_init(const float* __restrict__ x,
                       const float* __restrict__ theta,
                       float* __restrict__ bufA,
                       float* __restrict__ acc) {
    int i = blockIdx.x * blockDim.x + threadIdx.x;
    if (i >= N_NODES * F4) return;
    float4 xv = ((const float4*)x)[i];
    ((float4*)bufA)[i] = xv;
    float t0 = theta[0];
    float4 a;
    a.x = t0 * xv.x; a.y = t0 * xv.y; a.z = t0 * xv.z; a.w = t0 * xv.w;
    ((float4*)acc)[i] = a;
}

// ---------------------------------------------------------------- phase A: m_e[e,:] = de_w[e] * sum_v dv_is[v]*t[v,:]
// 32 lanes (1 float4 each) per edge, 8 edges per block
__global__ void k_phaseA(const float* __restrict__ tin,
                         const float* __restrict__ dv_is,
                         const float* __restrict__ de_w,
                         const int* __restrict__ edge_ptr,
                         const int* __restrict__ edge_node,
                         float* __restrict__ m_e) {
    int sub  = threadIdx.x >> 5;
    int lane = threadIdx.x & 31;
    int e = blockIdx.x * 8 + sub;
    if (e >= N_EDGES) return;
    int s = edge_ptr[e], t = edge_ptr[e + 1];
    float4 acc = make_float4(0.f, 0.f, 0.f, 0.f);
    for (int j = s; j < t; ++j) {
        int v = edge_node[j];
        float sc = dv_is[v];
        float4 xv = ((const float4*)tin)[v * F4 + lane];
        acc.x += sc * xv.x; acc.y += sc * xv.y;
        acc.z += sc * xv.z; acc.w += sc * xv.w;
    }
    float w = de_w[e];
    float4 o;
    o.x = acc.x * w; o.y = acc.y * w; o.z = acc.z * w; o.w = acc.w * w;
    ((float4*)m_e)[e * F4 + lane] = o;
}

// ---------------------------------------------------------------- phase B: p = dv_is[v]*sum_e m_e[e,:]
// t_out = ca*p + cb*t_prev (in-place over t_prev), acc += theta[k]*t_out
__global__ void k_phaseB(const float* __restrict__ m_e,
                         const float* __restrict__ dv_is,
                         const int* __restrict__ node_ptr,
                         const int* __restrict__ node_edge,
                         float* __restrict__ tio,    // reads t_prev, writes t_next
                         float* __restrict__ acc,
                         const float* __restrict__ theta, int k,
                         float ca, float cb) {
    int sub  = threadIdx.x >> 5;
    int lane = threadIdx.x & 31;
    int v = blockIdx.x * 8 + sub;
    if (v >= N_NODES) return;
    int s = node_ptr[v], t = node_ptr[v + 1];
    float4 sum = make_float4(0.f, 0.f, 0.f, 0.f);
    for (int j = s; j < t; ++j) {
        int e = node_edge[j];
        float4 me = ((const float4*)m_e)[e * F4 + lane];
        sum.x += me.x; sum.y += me.y; sum.z += me.z; sum.w += me.w;
    }
    float sc = dv_is[v];
    float th = theta[k];
    int idx = v * F4 + lane;
    float4 tp = ((const float4*)tio)[idx];
    float4 tn;
    tn.x = ca * sc * sum.x + cb * tp.x;
    tn.y = ca * sc * sum.y + cb * tp.y;
    tn.z = ca * sc * sum.z + cb * tp.z;
    tn.w = ca * sc * sum.w + cb * tp.w;
    ((float4*)tio)[idx] = tn;
    float4 a = ((const float4*)acc)[idx];
    a.x += th * tn.x; a.y += th * tn.y; a.z += th * tn.z; a.w += th * tn.w;
    ((float4*)acc)[idx] = a;
}

// ---------------------------------------------------------------- GEMM: out = relu(acc @ W^T + b)
// 64x64 tile, BK=64 staged in LDS (2 chunks), 256 threads, 4x4 micro-tile
__global__ __launch_bounds__(256) void k_gemm(const float* __restrict__ A,
                                              const float* __restrict__ W,
                                              const float* __restrict__ bias,
                                              float* __restrict__ out) {
    __shared__ __align__(16) float As[64][68];  // [k][m], pad to 68
    __shared__ __align__(16) float Ws[64][68];  // [k][h]
    int m0 = blockIdx.y * 64;
    int h0 = blockIdx.x * 64;
    int tid = (int)threadIdx.x;
    int ty = tid >> 4, tx = tid & 15;
    float cacc[4][4];
#pragma unroll
    for (int i = 0; i < 4; ++i)
#pragma unroll
        for (int j = 0; j < 4; ++j) cacc[i][j] = 0.f;

    for (int kb = 0; kb < F_IN / 64; ++kb) {
        // stage 64 rows x 64 k-values of A and W (transposed to [k][*])
#pragma unroll
        for (int i = 0; i < 4; ++i) {
            int c   = tid + i * 256;     // 0..1023
            int row = c >> 4;            // 0..63
            int k4  = c & 15;            // 0..15 (float4 index within 64-k chunk)
            int gr = m0 + row;
            float4 av = (gr < N_NODES) ? ((const float4*)A)[gr * F4 + kb * 16 + k4]
                                       : make_float4(0.f, 0.f, 0.f, 0.f);
            As[k4 * 4 + 0][row] = av.x; As[k4 * 4 + 1][row] = av.y;
            As[k4 * 4 + 2][row] = av.z; As[k4 * 4 + 3][row] = av.w;
            float4 wv = ((const float4*)W)[(h0 + row) * F4 + kb * 16 + k4];
            Ws[k4 * 4 + 0][row] = wv.x; Ws[k4 * 4 + 1][row] = wv.y;
            Ws[k4 * 4 + 2][row] = wv.z; Ws[k4 * 4 + 3][row] = wv.w;
        }
        __syncthreads();
#pragma unroll 4
        for (int kk = 0; kk < 64; ++kk) {
            float4 a = *(const float4*)&As[kk][ty * 4];
            float4 w = *(const float4*)&Ws[kk][tx * 4];
            float av[4] = {a.x, a.y, a.z, a.w};
            float wv[4] = {w.x, w.y, w.z, w.w};
#pragma unroll
            for (int i = 0; i < 4; ++i)
#pragma unroll
                for (int j = 0; j < 4; ++j) cacc[i][j] += av[i] * wv[j];
        }
        __syncthreads();
    }

    float4 bv = *(const float4*)&bias[h0 + tx * 4];
    float bb[4] = {bv.x, bv.y, bv.z, bv.w};
#pragma unroll
    for (int i = 0; i < 4; ++i) {
        int r = m0 + ty * 4 + i;
        if (r < N_NODES) {
            float4 o;
            o.x = fmaxf(cacc[i][0] + bb[0], 0.f);
            o.y = fmaxf(cacc[i][1] + bb[1], 0.f);
            o.z = fmaxf(cacc[i][2] + bb[2], 0.f);
            o.w = fmaxf(cacc[i][3] + bb[3], 0.f);
            ((float4*)out)[(r * HID + h0 + tx * 4) >> 2] = o;
        }
    }
}

// ----------------------------------------------------------------
extern "C" void kernel_launch(void* const* d_in, const int* in_sizes, int n_in,
                              void* d_out, int out_size, void* d_ws, size_t ws_size,
                              hipStream_t stream) {
    const float* x     = (const float*)d_in[0];
    const int*   hidx  = (const int*)d_in[1];    // int32! [2, NNZ] row-major
    const float* ew    = (const float*)d_in[2];
    const float* theta = (const float*)d_in[3];
    const float* w1    = (const float*)d_in[4];
    const float* b1    = (const float*)d_in[5];
    float*       out   = (float*)d_out;
    int kp1 = in_sizes[3];  // K+1 (= 11)

    // ---- scratch carved out of d_out (free until the final GEMM) ----
    float* bufA      = out;                                   // 6.4M floats
    float* bufB      = out + (size_t)N_NODES * F_IN;          // 6.4M floats
    float* m_e       = bufB + (size_t)N_NODES * F_IN;         // 1.28M floats
    int*   edge_node = (int*)(m_e + (size_t)N_EDGES * F_IN);  // 800k ints
    int*   node_edge = edge_node + NNZ;                       // 800k ints
    // total 62.7MB < out_size (25.6M floats = 102.4MB)

    // ---- d_ws: accv + small arrays (~27MB) ----
    char* ws = (char*)d_ws;
    size_t off = 0;
    auto alloc = [&](size_t bytes) -> void* {
        void* p = ws + off;
        off = (off + bytes + 255) & ~(size_t)255;
        return p;
    };
    float* accv     = (float*)alloc((size_t)N_NODES * F_IN * 4);
    float* d_v      = (float*)alloc((size_t)N_NODES * 4);
    float* dv_is    = (float*)alloc((size_t)N_NODES * 4);
    float* de_w     = (float*)alloc((size_t)N_EDGES * 4);
    int*   d_e_cnt  = (int*)alloc((size_t)N_EDGES * 4);
    int*   n_cnt    = (int*)alloc((size_t)N_NODES * 4);
    int*   edge_ptr = (int*)alloc((size_t)(N_EDGES + 1) * 4);
    int*   node_ptr = (int*)alloc((size_t)(N_NODES + 1) * 4);
    int*   edge_cur = (int*)alloc((size_t)N_EDGES * 4);
    int*   node_cur = (int*)alloc((size_t)N_NODES * 4);

    k_zero<<<(N_NODES + 255) / 256, 256, 0, stream>>>(d_v, d_e_cnt, n_cnt, edge_cur, node_cur);
    k_degrees<<<(NNZ + 255) / 256, 256, 0, stream>>>(hidx, ew, d_e_cnt, n_cnt, d_v);
    k_norms<<<(N_NODES + 255) / 256, 256, 0, stream>>>(d_v, d_e_cnt, ew, dv_is, de_w);
    k_scan<<<1, 1024, 0, stream>>>(d_e_cnt, N_EDGES, edge_ptr);
    k_scan<<<1, 1024, 0, stream>>>(n_cnt, N_NODES, node_ptr);
    k_fill<<<(NNZ + 255) / 256, 256, 0, stream>>>(hidx, edge_ptr, node_ptr,
                                                  edge_cur, node_cur, edge_node, node_edge);
    k_init<<<(N_NODES * F4 + 255) / 256, 256, 0, stream>>>(x, theta, bufA, accv);

    for (int k = 1; k < kp1; ++k) {
        const float* tin = (k & 1) ? bufA : bufB;   // T_{k-1}
        float*       tio = (k & 1) ? bufB : bufA;   // T_{k-2} -> T_k (in place)
        float ca = (k == 1) ? -1.f : -2.f;
        float cb = (k == 1) ? 0.f : -1.f;
        k_phaseA<<<N_EDGES / 8, 256, 0, stream>>>(tin, dv_is, de_w, edge_ptr, edge_node, m_e);
        k_phaseB<<<N_NODES / 8, 256, 0, stream>>>(m_e, dv_is, node_ptr, node_edge,
                                                  tio, accv, theta, k, ca, cb);
    }

    dim3 ggrid(HID / 64, (N_NODES + 63) / 64);
    k_gemm<<<ggrid, 256, 0, stream>>>(accv, w1, b1, out);
}

// Round 4
// 1666.419 us; speedup vs baseline: 1.0673x; 1.0673x over previous
//
#include <hip/hip_runtime.h>

// HypergraphGuidedChebNet on MI355X.
//   1. zero counters  2. degrees (atomic histograms)  3. norms
//   4. multi-block scans -> CSR ptrs  5. fill CSR (atomic cursors)
//   6. init acc/T0
//   7. 10x [phaseA edge-gather -> bf16 m_e, phaseB node-gather + Cheb + acc]
//   8. fp32 tiled GEMM, natural [m][k] LDS layout (conflict-free staging)
//
// Round 4 changes (theory: gemm 30% LDS-conflict cycles; scan hidden cost;
// phaseB gather-BW bound):
//   - GEMM: LDS [row][k4] float4 pad-17, b128 staging writes, float4-dot
//     micro-kernel. Predict 119us -> ~60us, conflicts 2.2e7 -> <3e6.
//   - Scans: 3-pass multi-block (was single-block over 50k = serial).
//   - m_e stored bf16 (RNE): phaseB gather bytes halve, m_e 2.56MB fits
//     per-XCD L2. Predict absmax ~2-3e-3 (threshold 7.85e-3).
//
// Memory plan: prop-loop scratch in d_out (free until GEMM):
//   d_out: [bufA 25.6MB][bufB 25.6MB][m_e(bf16) 2.56MB][edge_node][node_edge]
//   d_ws:  [accv 25.6MB][small arrays ~1MB]

#define N_NODES 50000
#define N_EDGES 10000
#define NNZ     800000
#define F_IN    128
#define HID     512
#define F4      (F_IN / 4)   // 32 float4 per row

// bf16 helpers (explicit RNE, bit-exact and header-version independent)
static __device__ __forceinline__ unsigned short f2bf(float f) {
    union { float f; unsigned u; } c; c.f = f;
    unsigned u = c.u;
    unsigned r = (u + 0x7fffu + ((u >> 16) & 1u)) >> 16;
    return (unsigned short)r;
}
static __device__ __forceinline__ float bf2f(unsigned short u) {
    union { float f; unsigned u; } c; c.u = ((unsigned)u) << 16;
    return c.f;
}

// ---------------------------------------------------------------- zero counters
__global__ void k_zero(float* __restrict__ d_v,
                       int* __restrict__ d_e_cnt,
                       int* __restrict__ n_cnt,
                       int* __restrict__ edge_cur,
                       int* __restrict__ node_cur) {
    int i = blockIdx.x * blockDim.x + threadIdx.x;
    if (i < N_NODES) { d_v[i] = 0.f; n_cnt[i] = 0; node_cur[i] = 0; }
    if (i < N_EDGES) { d_e_cnt[i] = 0; edge_cur[i] = 0; }
}

// ---------------------------------------------------------------- degrees
__global__ void k_degrees(const int* __restrict__ hidx,
                          const float* __restrict__ ew,
                          int* __restrict__ d_e_cnt,
                          int* __restrict__ n_cnt,
                          float* __restrict__ d_v) {
    int i = blockIdx.x * blockDim.x + threadIdx.x;
    if (i >= NNZ) return;
    int v = hidx[i];
    int e = hidx[NNZ + i];
    v = min(max(v, 0), N_NODES - 1);
    e = min(max(e, 0), N_EDGES - 1);
    atomicAdd(&d_e_cnt[e], 1);
    atomicAdd(&n_cnt[v], 1);
    atomicAdd(&d_v[v], ew[e]);
}

// ---------------------------------------------------------------- norms
__global__ void k_norms(const float* __restrict__ d_v,
                        const int* __restrict__ d_e_cnt,
                        const float* __restrict__ ew,
                        float* __restrict__ dv_is,
                        float* __restrict__ de_w) {
    int i = blockIdx.x * blockDim.x + threadIdx.x;
    if (i < N_NODES) {
        float d = d_v[i];
        dv_is[i] = (d > 0.f) ? rsqrtf(fmaxf(d, 1e-12f)) : 0.f;
    }
    if (i < N_EDGES) {
        int c = d_e_cnt[i];
        de_w[i] = ew[i] * ((c > 0) ? (1.f / (float)c) : 0.f);
    }
}

// ---------------------------------------------------------------- scan pass 1: per-block exclusive scan + block totals
__global__ __launch_bounds__(1024) void k_scan_blk(const int* __restrict__ counts, int n,
                                                   int* __restrict__ out,
                                                   int* __restrict__ partial) {
    __shared__ int sd[1024];
    int tid = (int)threadIdx.x;
    int i = blockIdx.x * 1024 + tid;
    int v = (i < n) ? counts[i] : 0;
    sd[tid] = v;
    __syncthreads();
    for (int off = 1; off < 1024; off <<= 1) {
        int t = (tid >= off) ? sd[tid - off] : 0;
        __syncthreads();
        sd[tid] += t;
        __syncthreads();
    }
    if (i < n) out[i] = sd[tid] - v;         // exclusive within block
    if (tid == 1023) partial[blockIdx.x] = sd[1023];
}

// ---------------------------------------------------------------- scan pass 2: wave-scan of block totals (nb <= 64)
__global__ void k_scan_top(int* __restrict__ partial, int nb, int* __restrict__ total_out) {
    int lane = (int)threadIdx.x;   // 64 threads
    int v = (lane < nb) ? partial[lane] : 0;
    int incl = v;
    for (int off = 1; off < 64; off <<= 1) {
        int t = __shfl_up(incl, off);
        if (lane >= off) incl += t;
    }
    if (lane < nb) partial[lane] = incl - v;  // exclusive
    if (lane == 63) *total_out = incl;        // grand total -> ptr[n]
}

// ---------------------------------------------------------------- scan pass 3: add block offsets
__global__ __launch_bounds__(1024) void k_scan_add(int* __restrict__ out, int n,
                                                   const int* __restrict__ partial) {
    int i = blockIdx.x * 1024 + (int)threadIdx.x;
    if (i < n) out[i] += partial[blockIdx.x];
}

// ---------------------------------------------------------------- CSR fill
__global__ void k_fill(const int* __restrict__ hidx,
                       const int* __restrict__ edge_ptr,
                       const int* __restrict__ node_ptr,
                       int* __restrict__ edge_cur,
                       int* __restrict__ node_cur,
                       int* __restrict__ edge_node,
                       int* __restrict__ node_edge) {
    int i = blockIdx.x * blockDim.x + threadIdx.x;
    if (i >= NNZ) return;
    int v = hidx[i];
    int e = hidx[NNZ + i];
    v = min(max(v, 0), N_NODES - 1);
    e = min(max(e, 0), N_EDGES - 1);
    int p = atomicAdd(&edge_cur[e], 1);
    edge_node[edge_ptr[e] + p] = v;
    int q = atomicAdd(&node_cur[v], 1);
    node_edge[node_ptr[v] + q] = e;
}

// ---------------------------------------------------------------- init: bufA = x (T0), acc = theta0 * x
__global__ void k_init(const float* __restrict__ x,
                       const float* __restrict__ theta,
                       float* __restrict__ bufA,
                       float* __restrict__ acc) {
    int i = blockIdx.x * blockDim.x + threadIdx.x;
    if (i >= N_NODES * F4) return;
    float4 xv = ((const float4*)x)[i];
    ((float4*)bufA)[i] = xv;
    float t0 = theta[0];
    float4 a;
    a.x = t0 * xv.x; a.y = t0 * xv.y; a.z = t0 * xv.z; a.w = t0 * xv.w;
    ((float4*)acc)[i] = a;
}

// ---------------------------------------------------------------- phase A: m_e[e,:] = bf16(de_w[e] * sum_v dv_is[v]*t[v,:])
// 32 lanes (1 float4 each) per edge, 8 edges per block
__global__ void k_phaseA(const float* __restrict__ tin,
                         const float* __restrict__ dv_is,
                         const float* __restrict__ de_w,
                         const int* __restrict__ edge_ptr,
                         const int* __restrict__ edge_node,
                         unsigned short* __restrict__ m_e) {  // bf16 [E][128]
    int sub  = threadIdx.x >> 5;
    int lane = threadIdx.x & 31;
    int e = blockIdx.x * 8 + sub;
    if (e >= N_EDGES) return;
    int s = edge_ptr[e], t = edge_ptr[e + 1];
    float4 acc = make_float4(0.f, 0.f, 0.f, 0.f);
    for (int j = s; j < t; ++j) {
        int v = edge_node[j];
        float sc = dv_is[v];
        float4 xv = ((const float4*)tin)[v * F4 + lane];
        acc.x += sc * xv.x; acc.y += sc * xv.y;
        acc.z += sc * xv.z; acc.w += sc * xv.w;
    }
    float w = de_w[e];
    ushort4 o;
    o.x = f2bf(acc.x * w); o.y = f2bf(acc.y * w);
    o.z = f2bf(acc.z * w); o.w = f2bf(acc.w * w);
    ((ushort4*)m_e)[e * 32 + lane] = o;   // 8B/lane, 256B/row coalesced
}

// ---------------------------------------------------------------- phase B: p = dv_is[v]*sum_e m_e[e,:]
// t_out = ca*p + cb*t_prev (in-place), acc += theta[k]*t_out
__global__ void k_phaseB(const unsigned short* __restrict__ m_e,  // bf16
                         const float* __restrict__ dv_is,
                         const int* __restrict__ node_ptr,
                         const int* __restrict__ node_edge,
                         float* __restrict__ tio,
                         float* __restrict__ acc,
                         const float* __restrict__ theta, int k,
                         float ca, float cb) {
    int sub  = threadIdx.x >> 5;
    int lane = threadIdx.x & 31;
    int v = blockIdx.x * 8 + sub;
    if (v >= N_NODES) return;
    int s = node_ptr[v], t = node_ptr[v + 1];
    float4 sum = make_float4(0.f, 0.f, 0.f, 0.f);
    for (int j = s; j < t; ++j) {
        int e = node_edge[j];
        ushort4 q = ((const ushort4*)m_e)[e * 32 + lane];
        sum.x += bf2f(q.x); sum.y += bf2f(q.y);
        sum.z += bf2f(q.z); sum.w += bf2f(q.w);
    }
    float sc = dv_is[v];
    float th = theta[k];
    int idx = v * F4 + lane;
    float4 tp = ((const float4*)tio)[idx];
    float4 tn;
    tn.x = ca * sc * sum.x + cb * tp.x;
    tn.y = ca * sc * sum.y + cb * tp.y;
    tn.z = ca * sc * sum.z + cb * tp.z;
    tn.w = ca * sc * sum.w + cb * tp.w;
    ((float4*)tio)[idx] = tn;
    float4 a = ((const float4*)acc)[idx];
    a.x += th * tn.x; a.y += th * tn.y; a.z += th * tn.z; a.w += th * tn.w;
    ((float4*)acc)[idx] = a;
}

// ---------------------------------------------------------------- GEMM: out = relu(acc @ W^T + b)
// 64x64 tile, BK=64 x2 chunks. LDS natural [row][k4] float4 layout, pad 17.
// Staging = single b128 write/lane (uniform bank spread). Micro-kernel =
// float4-dot: cacc[i][j] += dot(a[i], w[j]).
__global__ __launch_bounds__(256) void k_gemm(const float* __restrict__ A,
                                              const float* __restrict__ W,
                                              const float* __restrict__ bias,
                                              float* __restrict__ out) {
    __shared__ __align__(16) float4 As4[64 * 17];  // [row][k4], 17.4KB
    __shared__ __align__(16) float4 Ws4[64 * 17];
    int m0 = blockIdx.y * 64;
    int h0 = blockIdx.x * 64;
    int tid = (int)threadIdx.x;
    int ty = tid >> 4, tx = tid & 15;
    float cacc[4][4];
#pragma unroll
    for (int i = 0; i < 4; ++i)
#pragma unroll
        for (int j = 0; j < 4; ++j) cacc[i][j] = 0.f;

    const float4* A4 = (const float4*)A;
    const float4* W4 = (const float4*)W;

    for (int kb = 0; kb < 2; ++kb) {
#pragma unroll
        for (int i = 0; i < 4; ++i) {
            int c   = tid + i * 256;   // 0..1023
            int row = c >> 4;          // 0..63
            int k4  = c & 15;          // 0..15
            int gr = m0 + row;
            As4[row * 17 + k4] = (gr < N_NODES) ? A4[gr * F4 + kb * 16 + k4]
                                                : make_float4(0.f, 0.f, 0.f, 0.f);
            Ws4[row * 17 + k4] = W4[(h0 + row) * F4 + kb * 16 + k4];
        }
        __syncthreads();
#pragma unroll
        for (int k4 = 0; k4 < 16; ++k4) {
            float4 a[4], w[4];
#pragma unroll
            for (int i = 0; i < 4; ++i) a[i] = As4[(ty * 4 + i) * 17 + k4];
#pragma unroll
            for (int j = 0; j < 4; ++j) w[j] = Ws4[(tx * 4 + j) * 17 + k4];
#pragma unroll
            for (int i = 0; i < 4; ++i)
#pragma unroll
                for (int j = 0; j < 4; ++j) {
                    cacc[i][j] += a[i].x * w[j].x;
                    cacc[i][j] += a[i].y * w[j].y;
                    cacc[i][j] += a[i].z * w[j].z;
                    cacc[i][j] += a[i].w * w[j].w;
                }
        }
        __syncthreads();
    }

    float4 bv = *(const float4*)&bias[h0 + tx * 4];
    float bb[4] = {bv.x, bv.y, bv.z, bv.w};
#pragma unroll
    for (int i = 0; i < 4; ++i) {
        int r = m0 + ty * 4 + i;
        if (r < N_NODES) {
            float4 o;
            o.x = fmaxf(cacc[i][0] + bb[0], 0.f);
            o.y = fmaxf(cacc[i][1] + bb[1], 0.f);
            o.z = fmaxf(cacc[i][2] + bb[2], 0.f);
            o.w = fmaxf(cacc[i][3] + bb[3], 0.f);
            ((float4*)out)[(r * HID + h0 + tx * 4) >> 2] = o;
        }
    }
}

// ----------------------------------------------------------------
extern "C" void kernel_launch(void* const* d_in, const int* in_sizes, int n_in,
                              void* d_out, int out_size, void* d_ws, size_t ws_size,
                              hipStream_t stream) {
    const float* x     = (const float*)d_in[0];
    const int*   hidx  = (const int*)d_in[1];    // int32, [2, NNZ] row-major
    const float* ew    = (const float*)d_in[2];
    const float* theta = (const float*)d_in[3];
    const float* w1    = (const float*)d_in[4];
    const float* b1    = (const float*)d_in[5];
    float*       out   = (float*)d_out;
    int kp1 = in_sizes[3];  // K+1 (= 11)

    // ---- scratch carved out of d_out (free until the final GEMM) ----
    float*          bufA      = out;                                  // 6.4M floats
    float*          bufB      = out + (size_t)N_NODES * F_IN;         // 6.4M floats
    unsigned short* m_e       = (unsigned short*)(bufB + (size_t)N_NODES * F_IN);  // bf16, 1.28M elts
    int*            edge_node = (int*)(m_e + (size_t)N_EDGES * F_IN); // 800k ints
    int*            node_edge = edge_node + NNZ;                      // 800k ints

    // ---- d_ws: accv + small arrays ----
    char* ws = (char*)d_ws;
    size_t off = 0;
    auto alloc = [&](size_t bytes) -> void* {
        void* p = ws + off;
        off = (off + bytes + 255) & ~(size_t)255;
        return p;
    };
    float* accv     = (float*)alloc((size_t)N_NODES * F_IN * 4);
    float* d_v      = (float*)alloc((size_t)N_NODES * 4);
    float* dv_is    = (float*)alloc((size_t)N_NODES * 4);
    float* de_w     = (float*)alloc((size_t)N_EDGES * 4);
    int*   d_e_cnt  = (int*)alloc((size_t)N_EDGES * 4);
    int*   n_cnt    = (int*)alloc((size_t)N_NODES * 4);
    int*   edge_ptr = (int*)alloc((size_t)(N_EDGES + 1) * 4);
    int*   node_ptr = (int*)alloc((size_t)(N_NODES + 1) * 4);
    int*   edge_cur = (int*)alloc((size_t)N_EDGES * 4);
    int*   node_cur = (int*)alloc((size_t)N_NODES * 4);
    int*   part_e   = (int*)alloc(64 * 4);
    int*   part_n   = (int*)alloc(64 * 4);

    const int NB_E = (N_EDGES + 1023) / 1024;   // 10
    const int NB_N = (N_NODES + 1023) / 1024;   // 49

    k_zero<<<(N_NODES + 255) / 256, 256, 0, stream>>>(d_v, d_e_cnt, n_cnt, edge_cur, node_cur);
    k_degrees<<<(NNZ + 255) / 256, 256, 0, stream>>>(hidx, ew, d_e_cnt, n_cnt, d_v);
    k_norms<<<(N_NODES + 255) / 256, 256, 0, stream>>>(d_v, d_e_cnt, ew, dv_is, de_w);

    k_scan_blk<<<NB_E, 1024, 0, stream>>>(d_e_cnt, N_EDGES, edge_ptr, part_e);
    k_scan_top<<<1, 64, 0, stream>>>(part_e, NB_E, edge_ptr + N_EDGES);
    k_scan_add<<<NB_E, 1024, 0, stream>>>(edge_ptr, N_EDGES, part_e);

    k_scan_blk<<<NB_N, 1024, 0, stream>>>(n_cnt, N_NODES, node_ptr, part_n);
    k_scan_top<<<1, 64, 0, stream>>>(part_n, NB_N, node_ptr + N_NODES);
    k_scan_add<<<NB_N, 1024, 0, stream>>>(node_ptr, N_NODES, part_n);

    k_fill<<<(NNZ + 255) / 256, 256, 0, stream>>>(hidx, edge_ptr, node_ptr,
                                                  edge_cur, node_cur, edge_node, node_edge);
    k_init<<<(N_NODES * F4 + 255) / 256, 256, 0, stream>>>(x, theta, bufA, accv);

    for (int k = 1; k < kp1; ++k) {
        const float* tin = (k & 1) ? bufA : bufB;   // T_{k-1}
        float*       tio = (k & 1) ? bufB : bufA;   // T_{k-2} -> T_k (in place)
        float ca = (k == 1) ? -1.f : -2.f;
        float cb = (k == 1) ? 0.f : -1.f;
        k_phaseA<<<N_EDGES / 8, 256, 0, stream>>>(tin, dv_is, de_w, edge_ptr, edge_node, m_e);
        k_phaseB<<<N_NODES / 8, 256, 0, stream>>>(m_e, dv_is, node_ptr, node_edge,
                                                  tio, accv, theta, k, ca, cb);
    }

    dim3 ggrid(HID / 64, (N_NODES + 63) / 64);
    k_gemm<<<ggrid, 256, 0, stream>>>(accv, w1, b1, out);
}

// Round 5
// 1183.775 us; speedup vs baseline: 1.5024x; 1.4077x over previous
//
#include <hip/hip_runtime.h>

// HypergraphGuidedChebNet on MI355X.
//   1. zero  2. degrees  3. norms  4. multi-block scans -> CSR
//   5. fill CSR  6. init (bf16 T0, fp32 acc)
//   7. 10x [phaseA edge-gather (bf16 in/out), phaseB node-gather + Cheb + acc]
//   8. fp32 GEMM, conflict-free interleaved micro-tile
//
// Round 5 changes:
//   - T buffers bf16 (state stored bf16, arithmetic fp32, acc fp32 from
//     unrounded t_next). phaseA gather bytes halve: 410 -> 205 MB/iter,
//     tin 12.8MB (L2-resident). Predict phases ~2x faster, absmax ~4e-3.
//   - GEMM micro-tile remapped: rows ty+16i, cols tx+16j. w-reads now step
//     1 row/lane (2-way bank alias = free) instead of 4 rows (8-way).
//     r4's 68-float row stride made stride-4-row reads fold into 2 bank
//     groups -> 3.8e7 conflicts. Predict 144 -> ~65us, conflicts <2e6.
//   - Gather loops unroll-2 with index prefetch.
//
// d_out scratch: [bufA 12.8MB][bufB 12.8MB][m_e 2.56MB][edge_node][node_edge]
// d_ws: [accv 25.6MB][small arrays ~1MB]

#define N_NODES 50000
#define N_EDGES 10000
#define NNZ     800000
#define F_IN    128
#define HID     512
#define F4      (F_IN / 4)   // 32 float4 per fp32 row
#define U4      32           // 32 ushort4 per bf16 row

static __device__ __forceinline__ unsigned short f2bf(float f) {
    union { float f; unsigned u; } c; c.f = f;
    unsigned u = c.u;
    unsigned r = (u + 0x7fffu + ((u >> 16) & 1u)) >> 16;
    return (unsigned short)r;
}
static __device__ __forceinline__ float bf2f(unsigned short u) {
    union { float f; unsigned u; } c; c.u = ((unsigned)u) << 16;
    return c.f;
}

// ---------------------------------------------------------------- zero counters
__global__ void k_zero(float* __restrict__ d_v,
                       int* __restrict__ d_e_cnt,
                       int* __restrict__ n_cnt,
                       int* __restrict__ edge_cur,
                       int* __restrict__ node_cur) {
    int i = blockIdx.x * blockDim.x + threadIdx.x;
    if (i < N_NODES) { d_v[i] = 0.f; n_cnt[i] = 0; node_cur[i] = 0; }
    if (i < N_EDGES) { d_e_cnt[i] = 0; edge_cur[i] = 0; }
}

// ---------------------------------------------------------------- degrees
__global__ void k_degrees(const int* __restrict__ hidx,
                          const float* __restrict__ ew,
                          int* __restrict__ d_e_cnt,
                          int* __restrict__ n_cnt,
                          float* __restrict__ d_v) {
    int i = blockIdx.x * blockDim.x + threadIdx.x;
    if (i >= NNZ) return;
    int v = hidx[i];
    int e = hidx[NNZ + i];
    v = min(max(v, 0), N_NODES - 1);
    e = min(max(e, 0), N_EDGES - 1);
    atomicAdd(&d_e_cnt[e], 1);
    atomicAdd(&n_cnt[v], 1);
    atomicAdd(&d_v[v], ew[e]);
}

// ---------------------------------------------------------------- norms
__global__ void k_norms(const float* __restrict__ d_v,
                        const int* __restrict__ d_e_cnt,
                        const float* __restrict__ ew,
                        float* __restrict__ dv_is,
                        float* __restrict__ de_w) {
    int i = blockIdx.x * blockDim.x + threadIdx.x;
    if (i < N_NODES) {
        float d = d_v[i];
        dv_is[i] = (d > 0.f) ? rsqrtf(fmaxf(d, 1e-12f)) : 0.f;
    }
    if (i < N_EDGES) {
        int c = d_e_cnt[i];
        de_w[i] = ew[i] * ((c > 0) ? (1.f / (float)c) : 0.f);
    }
}

// ---------------------------------------------------------------- scan p1
__global__ __launch_bounds__(1024) void k_scan_blk(const int* __restrict__ counts, int n,
                                                   int* __restrict__ out,
                                                   int* __restrict__ partial) {
    __shared__ int sd[1024];
    int tid = (int)threadIdx.x;
    int i = blockIdx.x * 1024 + tid;
    int v = (i < n) ? counts[i] : 0;
    sd[tid] = v;
    __syncthreads();
    for (int off = 1; off < 1024; off <<= 1) {
        int t = (tid >= off) ? sd[tid - off] : 0;
        __syncthreads();
        sd[tid] += t;
        __syncthreads();
    }
    if (i < n) out[i] = sd[tid] - v;
    if (tid == 1023) partial[blockIdx.x] = sd[1023];
}

// ---------------------------------------------------------------- scan p2 (nb <= 64)
__global__ void k_scan_top(int* __restrict__ partial, int nb, int* __restrict__ total_out) {
    int lane = (int)threadIdx.x;
    int v = (lane < nb) ? partial[lane] : 0;
    int incl = v;
    for (int off = 1; off < 64; off <<= 1) {
        int t = __shfl_up(incl, off);
        if (lane >= off) incl += t;
    }
    if (lane < nb) partial[lane] = incl - v;
    if (lane == 63) *total_out = incl;
}

// ---------------------------------------------------------------- scan p3
__global__ __launch_bounds__(1024) void k_scan_add(int* __restrict__ out, int n,
                                                   const int* __restrict__ partial) {
    int i = blockIdx.x * 1024 + (int)threadIdx.x;
    if (i < n) out[i] += partial[blockIdx.x];
}

// ---------------------------------------------------------------- CSR fill
__global__ void k_fill(const int* __restrict__ hidx,
                       const int* __restrict__ edge_ptr,
                       const int* __restrict__ node_ptr,
                       int* __restrict__ edge_cur,
                       int* __restrict__ node_cur,
                       int* __restrict__ edge_node,
                       int* __restrict__ node_edge) {
    int i = blockIdx.x * blockDim.x + threadIdx.x;
    if (i >= NNZ) return;
    int v = hidx[i];
    int e = hidx[NNZ + i];
    v = min(max(v, 0), N_NODES - 1);
    e = min(max(e, 0), N_EDGES - 1);
    int p = atomicAdd(&edge_cur[e], 1);
    edge_node[edge_ptr[e] + p] = v;
    int q = atomicAdd(&node_cur[v], 1);
    node_edge[node_ptr[v] + q] = e;
}

// ---------------------------------------------------------------- init: bufA = bf16(x), acc = theta0 * x
__global__ void k_init(const float* __restrict__ x,
                       const float* __restrict__ theta,
                       unsigned short* __restrict__ bufA,   // bf16
                       float* __restrict__ acc) {
    int i = blockIdx.x * blockDim.x + threadIdx.x;
    if (i >= N_NODES * F4) return;
    float4 xv = ((const float4*)x)[i];
    ushort4 q;
    q.x = f2bf(xv.x); q.y = f2bf(xv.y); q.z = f2bf(xv.z); q.w = f2bf(xv.w);
    ((ushort4*)bufA)[i] = q;
    float t0 = theta[0];
    float4 a;
    a.x = t0 * xv.x; a.y = t0 * xv.y; a.z = t0 * xv.z; a.w = t0 * xv.w;
    ((float4*)acc)[i] = a;
}

// ---------------------------------------------------------------- phase A
// m_e[e,:] = bf16(de_w[e] * sum_v dv_is[v]*t[v,:]); t is bf16.
// 32 lanes (ushort4 = 4 feats each) per edge, 8 edges/block.
__global__ void k_phaseA(const unsigned short* __restrict__ tin,   // bf16 [N][128]
                         const float* __restrict__ dv_is,
                         const float* __restrict__ de_w,
                         const int* __restrict__ edge_ptr,
                         const int* __restrict__ edge_node,
                         unsigned short* __restrict__ m_e) {       // bf16 [E][128]
    int sub  = threadIdx.x >> 5;
    int lane = threadIdx.x & 31;
    int e = blockIdx.x * 8 + sub;
    int s = edge_ptr[e], t = edge_ptr[e + 1];
    float ax = 0.f, ay = 0.f, az = 0.f, aw = 0.f;
    const ushort4* t4 = (const ushort4*)tin;
    int j = s;
    for (; j + 1 < t; j += 2) {
        int v0 = edge_node[j];
        int v1 = edge_node[j + 1];
        float s0 = dv_is[v0];
        float s1 = dv_is[v1];
        ushort4 q0 = t4[v0 * U4 + lane];
        ushort4 q1 = t4[v1 * U4 + lane];
        ax += s0 * bf2f(q0.x); ay += s0 * bf2f(q0.y);
        az += s0 * bf2f(q0.z); aw += s0 * bf2f(q0.w);
        ax += s1 * bf2f(q1.x); ay += s1 * bf2f(q1.y);
        az += s1 * bf2f(q1.z); aw += s1 * bf2f(q1.w);
    }
    if (j < t) {
        int v0 = edge_node[j];
        float s0 = dv_is[v0];
        ushort4 q0 = t4[v0 * U4 + lane];
        ax += s0 * bf2f(q0.x); ay += s0 * bf2f(q0.y);
        az += s0 * bf2f(q0.z); aw += s0 * bf2f(q0.w);
    }
    float w = de_w[e];
    ushort4 o;
    o.x = f2bf(ax * w); o.y = f2bf(ay * w);
    o.z = f2bf(az * w); o.w = f2bf(aw * w);
    ((ushort4*)m_e)[e * U4 + lane] = o;
}

// ---------------------------------------------------------------- phase B
// p = dv_is[v]*sum_e m_e[e,:]; t_next = ca*p + cb*t_prev (bf16 state, fp32 math)
// acc += theta[k]*t_next (unrounded).
__global__ void k_phaseB(const unsigned short* __restrict__ m_e,   // bf16
                         const float* __restrict__ dv_is,
                         const int* __restrict__ node_ptr,
                         const int* __restrict__ node_edge,
                         unsigned short* __restrict__ tio,          // bf16 state
                         float* __restrict__ acc,
                         const float* __restrict__ theta, int k,
                         float ca, float cb) {
    int sub  = threadIdx.x >> 5;
    int lane = threadIdx.x & 31;
    int v = blockIdx.x * 8 + sub;
    int s = node_ptr[v], t = node_ptr[v + 1];
    float sx = 0.f, sy = 0.f, sz = 0.f, sw = 0.f;
    const ushort4* me4 = (const ushort4*)m_e;
    int j = s;
    for (; j + 1 < t; j += 2) {
        int e0 = node_edge[j];
        int e1 = node_edge[j + 1];
        ushort4 q0 = me4[e0 * U4 + lane];
        ushort4 q1 = me4[e1 * U4 + lane];
        sx += bf2f(q0.x) + bf2f(q1.x);
        sy += bf2f(q0.y) + bf2f(q1.y);
        sz += bf2f(q0.z) + bf2f(q1.z);
        sw += bf2f(q0.w) + bf2f(q1.w);
    }
    if (j < t) {
        int e0 = node_edge[j];
        ushort4 q0 = me4[e0 * U4 + lane];
        sx += bf2f(q0.x); sy += bf2f(q0.y);
        sz += bf2f(q0.z); sw += bf2f(q0.w);
    }
    float sc = dv_is[v];
    float th = theta[k];
    int idx = v * U4 + lane;
    ushort4 tp = ((const ushort4*)tio)[idx];
    float tnx = ca * sc * sx + cb * bf2f(tp.x);
    float tny = ca * sc * sy + cb * bf2f(tp.y);
    float tnz = ca * sc * sz + cb * bf2f(tp.z);
    float tnw = ca * sc * sw + cb * bf2f(tp.w);
    ushort4 tn;
    tn.x = f2bf(tnx); tn.y = f2bf(tny); tn.z = f2bf(tnz); tn.w = f2bf(tnw);
    ((ushort4*)tio)[idx] = tn;
    float4 a = ((const float4*)acc)[idx];
    a.x += th * tnx; a.y += th * tny; a.z += th * tnz; a.w += th * tnw;
    ((float4*)acc)[idx] = a;
}

// ---------------------------------------------------------------- GEMM: out = relu(acc @ W^T + b)
// 64x64 tile, BK=64 x2. LDS [row][k4] float4 pad-17. Interleaved micro-tile:
// thread (ty,tx) -> rows ty+16i, cols tx+16j. w-reads step 1 row/lane
// (2-way bank alias = free); a-reads broadcast. Conflict-free.
__global__ __launch_bounds__(256) void k_gemm(const float* __restrict__ A,
                                              const float* __restrict__ W,
                                              const float* __restrict__ bias,
                                              float* __restrict__ out) {
    __shared__ __align__(16) float4 As4[64 * 17];
    __shared__ __align__(16) float4 Ws4[64 * 17];
    int m0 = blockIdx.y * 64;
    int h0 = blockIdx.x * 64;
    int tid = (int)threadIdx.x;
    int ty = tid >> 4, tx = tid & 15;
    float cacc[4][4];
#pragma unroll
    for (int i = 0; i < 4; ++i)
#pragma unroll
        for (int j = 0; j < 4; ++j) cacc[i][j] = 0.f;

    const float4* A4 = (const float4*)A;
    const float4* W4 = (const float4*)W;

    for (int kb = 0; kb < 2; ++kb) {
#pragma unroll
        for (int i = 0; i < 4; ++i) {
            int c   = tid + i * 256;   // 0..1023
            int row = c >> 4;          // 0..63
            int k4  = c & 15;          // 0..15
            int gr = m0 + row;
            As4[row * 17 + k4] = (gr < N_NODES) ? A4[gr * F4 + kb * 16 + k4]
                                                : make_float4(0.f, 0.f, 0.f, 0.f);
            Ws4[row * 17 + k4] = W4[(h0 + row) * F4 + kb * 16 + k4];
        }
        __syncthreads();
#pragma unroll
        for (int k4 = 0; k4 < 16; ++k4) {
            float4 a[4], w[4];
#pragma unroll
            for (int i = 0; i < 4; ++i) a[i] = As4[(ty + 16 * i) * 17 + k4];
#pragma unroll
            for (int j = 0; j < 4; ++j) w[j] = Ws4[(tx + 16 * j) * 17 + k4];
#pragma unroll
            for (int i = 0; i < 4; ++i)
#pragma unroll
                for (int j = 0; j < 4; ++j) {
                    cacc[i][j] += a[i].x * w[j].x;
                    cacc[i][j] += a[i].y * w[j].y;
                    cacc[i][j] += a[i].z * w[j].z;
                    cacc[i][j] += a[i].w * w[j].w;
                }
        }
        __syncthreads();
    }

    float bb[4];
#pragma unroll
    for (int j = 0; j < 4; ++j) bb[j] = bias[h0 + tx + 16 * j];
#pragma unroll
    for (int i = 0; i < 4; ++i) {
        int r = m0 + ty + 16 * i;
        if (r < N_NODES) {
#pragma unroll
            for (int j = 0; j < 4; ++j) {
                out[(size_t)r * HID + h0 + tx + 16 * j] =
                    fmaxf(cacc[i][j] + bb[j], 0.f);
            }
        }
    }
}

// ----------------------------------------------------------------
extern "C" void kernel_launch(void* const* d_in, const int* in_sizes, int n_in,
                              void* d_out, int out_size, void* d_ws, size_t ws_size,
                              hipStream_t stream) {
    const float* x     = (const float*)d_in[0];
    const int*   hidx  = (const int*)d_in[1];    // int32, [2, NNZ] row-major
    const float* ew    = (const float*)d_in[2];
    const float* theta = (const float*)d_in[3];
    const float* w1    = (const float*)d_in[4];
    const float* b1    = (const float*)d_in[5];
    float*       out   = (float*)d_out;
    int kp1 = in_sizes[3];  // K+1 (= 11)

    // ---- scratch carved out of d_out (free until the final GEMM) ----
    unsigned short* bufA      = (unsigned short*)out;                 // bf16 6.4M
    unsigned short* bufB      = bufA + (size_t)N_NODES * F_IN;        // bf16 6.4M
    unsigned short* m_e       = bufB + (size_t)N_NODES * F_IN;        // bf16 1.28M
    int*            edge_node = (int*)(m_e + (size_t)N_EDGES * F_IN); // 800k ints
    int*            node_edge = edge_node + NNZ;                      // 800k ints
    // total ~34.6MB < 102.4MB

    // ---- d_ws ----
    char* ws = (char*)d_ws;
    size_t off = 0;
    auto alloc = [&](size_t bytes) -> void* {
        void* p = ws + off;
        off = (off + bytes + 255) & ~(size_t)255;
        return p;
    };
    float* accv     = (float*)alloc((size_t)N_NODES * F_IN * 4);
    float* d_v      = (float*)alloc((size_t)N_NODES * 4);
    float* dv_is    = (float*)alloc((size_t)N_NODES * 4);
    float* de_w     = (float*)alloc((size_t)N_EDGES * 4);
    int*   d_e_cnt  = (int*)alloc((size_t)N_EDGES * 4);
    int*   n_cnt    = (int*)alloc((size_t)N_NODES * 4);
    int*   edge_ptr = (int*)alloc((size_t)(N_EDGES + 1) * 4);
    int*   node_ptr = (int*)alloc((size_t)(N_NODES + 1) * 4);
    int*   edge_cur = (int*)alloc((size_t)N_EDGES * 4);
    int*   node_cur = (int*)alloc((size_t)N_NODES * 4);
    int*   part_e   = (int*)alloc(64 * 4);
    int*   part_n   = (int*)alloc(64 * 4);

    const int NB_E = (N_EDGES + 1023) / 1024;   // 10
    const int NB_N = (N_NODES + 1023) / 1024;   // 49

    k_zero<<<(N_NODES + 255) / 256, 256, 0, stream>>>(d_v, d_e_cnt, n_cnt, edge_cur, node_cur);
    k_degrees<<<(NNZ + 255) / 256, 256, 0, stream>>>(hidx, ew, d_e_cnt, n_cnt, d_v);
    k_norms<<<(N_NODES + 255) / 256, 256, 0, stream>>>(d_v, d_e_cnt, ew, dv_is, de_w);

    k_scan_blk<<<NB_E, 1024, 0, stream>>>(d_e_cnt, N_EDGES, edge_ptr, part_e);
    k_scan_top<<<1, 64, 0, stream>>>(part_e, NB_E, edge_ptr + N_EDGES);
    k_scan_add<<<NB_E, 1024, 0, stream>>>(edge_ptr, N_EDGES, part_e);

    k_scan_blk<<<NB_N, 1024, 0, stream>>>(n_cnt, N_NODES, node_ptr, part_n);
    k_scan_top<<<1, 64, 0, stream>>>(part_n, NB_N, node_ptr + N_NODES);
    k_scan_add<<<NB_N, 1024, 0, stream>>>(node_ptr, N_NODES, part_n);

    k_fill<<<(NNZ + 255) / 256, 256, 0, stream>>>(hidx, edge_ptr, node_ptr,
                                                  edge_cur, node_cur, edge_node, node_edge);
    k_init<<<(N_NODES * F4 + 255) / 256, 256, 0, stream>>>(x, theta, bufA, accv);

    for (int k = 1; k < kp1; ++k) {
        const unsigned short* tin = (k & 1) ? bufA : bufB;   // T_{k-1}
        unsigned short*       tio = (k & 1) ? bufB : bufA;   // T_{k-2} -> T_k
        float ca = (k == 1) ? -1.f : -2.f;
        float cb = (k == 1) ? 0.f : -1.f;
        k_phaseA<<<N_EDGES / 8, 256, 0, stream>>>(tin, dv_is, de_w, edge_ptr, edge_node, m_e);
        k_phaseB<<<N_NODES / 8, 256, 0, stream>>>(m_e, dv_is, node_ptr, node_edge,
                                                  tio, accv, theta, k, ca, cb);
    }

    dim3 ggrid(HID / 64, (N_NODES + 63) / 64);
    k_gemm<<<ggrid, 256, 0, stream>>>(accv, w1, b1, out);
}

// Round 6
// 1028.239 us; speedup vs baseline: 1.7297x; 1.1513x over previous
//
#include <hip/hip_runtime.h>

// HypergraphGuidedChebNet on MI355X.
//   1. zero padded counters  2. degrees (padded atomics + rank capture)
//   3. scans (strided)  4. fill CSR (NO atomics, uses ranks)
//   5. norms2 (d_v from CSR, de_w from ptr diffs)  6. init
//   7. 10x [phaseA edge-gather, phaseB node-gather + Cheb + acc] (bf16, 16B/lane)
//   8. fp32 GEMM (interleaved micro-tile, conflict-free)
//
// Round 6 theory: k_degrees' 116us @ VALUBusy 0.2% = memory-side atomic
// line contention (800k ops / 625 lines = 1280 ops/line on d_e_cnt).
//   - counters padded to 1 int per 64B line (stride 16): 1280 -> 80 ops/line.
//   - atomicAdd return value = rank within bin -> k_fill needs no atomics.
//   - d_v computed after CSR build (no atomics at all for it).
//   - phase gathers widened to 16 lanes x uint4 (8 bf16 = 16B/lane).
//
// d_out scratch (free until final GEMM): bufA/bufB/m_e/edge_node/node_edge/
//   rank_e/rank_v/d_e_cnt16/n_cnt16  (~45MB of 102.4MB)
// d_ws: accv 25.6MB + small arrays (~26MB, under r3's proven 27MB)

#define N_NODES 50000
#define N_EDGES 10000
#define NNZ     800000
#define F_IN    128
#define HID     512
#define F4      (F_IN / 4)   // 32 float4 per fp32 row
#define R16     16           // 16 uint4 per bf16 row (8 bf16 per uint4)

static __device__ __forceinline__ unsigned short f2bf(float f) {
    union { float f; unsigned u; } c; c.f = f;
    unsigned u = c.u;
    unsigned r = (u + 0x7fffu + ((u >> 16) & 1u)) >> 16;
    return (unsigned short)r;
}
static __device__ __forceinline__ float blo(unsigned u) {
    union { unsigned u; float f; } c; c.u = u << 16; return c.f;
}
static __device__ __forceinline__ float bhi(unsigned u) {
    union { unsigned u; float f; } c; c.u = u & 0xffff0000u; return c.f;
}
static __device__ __forceinline__ unsigned pack2(float lo, float hi) {
    return (unsigned)f2bf(lo) | ((unsigned)f2bf(hi) << 16);
}

// ---------------------------------------------------------------- zero padded counters
__global__ void k_zero2(int* __restrict__ d_e_cnt16, int* __restrict__ n_cnt16) {
    int i = blockIdx.x * blockDim.x + threadIdx.x;
    if (i < N_NODES * 16) n_cnt16[i] = 0;
    if (i < N_EDGES * 16) d_e_cnt16[i] = 0;
}

// ---------------------------------------------------------------- degrees + rank capture
__global__ void k_degrees(const int* __restrict__ hidx,
                          int* __restrict__ d_e_cnt16,   // stride-16 padded
                          int* __restrict__ n_cnt16,     // stride-16 padded
                          int* __restrict__ rank_e,
                          int* __restrict__ rank_v) {
    int i = blockIdx.x * blockDim.x + threadIdx.x;
    if (i >= NNZ) return;
    int v = hidx[i];
    int e = hidx[NNZ + i];
    v = min(max(v, 0), N_NODES - 1);
    e = min(max(e, 0), N_EDGES - 1);
    rank_e[i] = atomicAdd(&d_e_cnt16[e << 4], 1);
    rank_v[i] = atomicAdd(&n_cnt16[v << 4], 1);
}

// ---------------------------------------------------------------- scan p1 (strided counts)
__global__ __launch_bounds__(1024) void k_scan_blk(const int* __restrict__ counts, int n,
                                                   int stride,
                                                   int* __restrict__ out,
                                                   int* __restrict__ partial) {
    __shared__ int sd[1024];
    int tid = (int)threadIdx.x;
    int i = blockIdx.x * 1024 + tid;
    int v = (i < n) ? counts[(size_t)i * stride] : 0;
    sd[tid] = v;
    __syncthreads();
    for (int off = 1; off < 1024; off <<= 1) {
        int t = (tid >= off) ? sd[tid - off] : 0;
        __syncthreads();
        sd[tid] += t;
        __syncthreads();
    }
    if (i < n) out[i] = sd[tid] - v;
    if (tid == 1023) partial[blockIdx.x] = sd[1023];
}

// ---------------------------------------------------------------- scan p2 (nb <= 64)
__global__ void k_scan_top(int* __restrict__ partial, int nb, int* __restrict__ total_out) {
    int lane = (int)threadIdx.x;
    int v = (lane < nb) ? partial[lane] : 0;
    int incl = v;
    for (int off = 1; off < 64; off <<= 1) {
        int t = __shfl_up(incl, off);
        if (lane >= off) incl += t;
    }
    if (lane < nb) partial[lane] = incl - v;
    if (lane == 63) *total_out = incl;
}

// ---------------------------------------------------------------- scan p3
__global__ __launch_bounds__(1024) void k_scan_add(int* __restrict__ out, int n,
                                                   const int* __restrict__ partial) {
    int i = blockIdx.x * 1024 + (int)threadIdx.x;
    if (i < n) out[i] += partial[blockIdx.x];
}

// ---------------------------------------------------------------- CSR fill (atomic-free)
__global__ void k_fill(const int* __restrict__ hidx,
                       const int* __restrict__ edge_ptr,
                       const int* __restrict__ node_ptr,
                       const int* __restrict__ rank_e,
                       const int* __restrict__ rank_v,
                       int* __restrict__ edge_node,
                       int* __restrict__ node_edge) {
    int i = blockIdx.x * blockDim.x + threadIdx.x;
    if (i >= NNZ) return;
    int v = hidx[i];
    int e = hidx[NNZ + i];
    v = min(max(v, 0), N_NODES - 1);
    e = min(max(e, 0), N_EDGES - 1);
    edge_node[edge_ptr[e] + rank_e[i]] = v;
    node_edge[node_ptr[v] + rank_v[i]] = e;
}

// ---------------------------------------------------------------- norms from CSR (no atomics)
__global__ void k_norms2(const float* __restrict__ ew,
                         const int* __restrict__ edge_ptr,
                         const int* __restrict__ node_ptr,
                         const int* __restrict__ node_edge,
                         float* __restrict__ dv_is,
                         float* __restrict__ de_w) {
    int i = blockIdx.x * blockDim.x + threadIdx.x;
    if (i < N_NODES) {
        int s = node_ptr[i], t = node_ptr[i + 1];
        float d = 0.f;
        for (int j = s; j < t; ++j) d += ew[node_edge[j]];
        dv_is[i] = (d > 0.f) ? rsqrtf(fmaxf(d, 1e-12f)) : 0.f;
    }
    if (i < N_EDGES) {
        int c = edge_ptr[i + 1] - edge_ptr[i];
        de_w[i] = ew[i] * ((c > 0) ? (1.f / (float)c) : 0.f);
    }
}

// ---------------------------------------------------------------- init: bufA = bf16(x), acc = theta0 * x
// thread handles 8 feats: 2 float4 reads, 1 uint4 bf16 write, 2 float4 acc writes
__global__ void k_init(const float* __restrict__ x,
                       const float* __restrict__ theta,
                       uint4* __restrict__ bufA,    // bf16-packed
                       float* __restrict__ acc) {
    int i = blockIdx.x * blockDim.x + threadIdx.x;
    if (i >= N_NODES * R16) return;
    float4 x0 = ((const float4*)x)[2 * i];
    float4 x1 = ((const float4*)x)[2 * i + 1];
    uint4 q;
    q.x = pack2(x0.x, x0.y); q.y = pack2(x0.z, x0.w);
    q.z = pack2(x1.x, x1.y); q.w = pack2(x1.z, x1.w);
    bufA[i] = q;
    float t0 = theta[0];
    float4 a0, a1;
    a0.x = t0 * x0.x; a0.y = t0 * x0.y; a0.z = t0 * x0.z; a0.w = t0 * x0.w;
    a1.x = t0 * x1.x; a1.y = t0 * x1.y; a1.z = t0 * x1.z; a1.w = t0 * x1.w;
    ((float4*)acc)[2 * i]     = a0;
    ((float4*)acc)[2 * i + 1] = a1;
}

// ---------------------------------------------------------------- phase A
// m_e[e,:] = bf16(de_w[e] * sum_v dv_is[v]*t[v,:]);  16 lanes x 8 bf16 (16B) per row
__global__ void k_phaseA(const uint4* __restrict__ tin,    // bf16 [N][128]
                         const float* __restrict__ dv_is,
                         const float* __restrict__ de_w,
                         const int* __restrict__ edge_ptr,
                         const int* __restrict__ edge_node,
                         uint4* __restrict__ m_e) {         // bf16 [E][128]
    int sub  = threadIdx.x >> 4;   // 0..15
    int lane = threadIdx.x & 15;
    int e = blockIdx.x * 16 + sub;
    int s = edge_ptr[e], t = edge_ptr[e + 1];
    float a0=0.f,a1=0.f,a2=0.f,a3=0.f,a4=0.f,a5=0.f,a6=0.f,a7=0.f;
    int j = s;
    for (; j + 1 < t; j += 2) {
        int v0 = edge_node[j];
        int v1 = edge_node[j + 1];
        float s0 = dv_is[v0];
        float s1 = dv_is[v1];
        uint4 q0 = tin[v0 * R16 + lane];
        uint4 q1 = tin[v1 * R16 + lane];
        a0 += s0 * blo(q0.x); a1 += s0 * bhi(q0.x);
        a2 += s0 * blo(q0.y); a3 += s0 * bhi(q0.y);
        a4 += s0 * blo(q0.z); a5 += s0 * bhi(q0.z);
        a6 += s0 * blo(q0.w); a7 += s0 * bhi(q0.w);
        a0 += s1 * blo(q1.x); a1 += s1 * bhi(q1.x);
        a2 += s1 * blo(q1.y); a3 += s1 * bhi(q1.y);
        a4 += s1 * blo(q1.z); a5 += s1 * bhi(q1.z);
        a6 += s1 * blo(q1.w); a7 += s1 * bhi(q1.w);
    }
    if (j < t) {
        int v0 = edge_node[j];
        float s0 = dv_is[v0];
        uint4 q0 = tin[v0 * R16 + lane];
        a0 += s0 * blo(q0.x); a1 += s0 * bhi(q0.x);
        a2 += s0 * blo(q0.y); a3 += s0 * bhi(q0.y);
        a4 += s0 * blo(q0.z); a5 += s0 * bhi(q0.z);
        a6 += s0 * blo(q0.w); a7 += s0 * bhi(q0.w);
    }
    float w = de_w[e];
    uint4 o;
    o.x = pack2(a0 * w, a1 * w); o.y = pack2(a2 * w, a3 * w);
    o.z = pack2(a4 * w, a5 * w); o.w = pack2(a6 * w, a7 * w);
    m_e[e * R16 + lane] = o;
}

// ---------------------------------------------------------------- phase B
// p = dv_is[v]*sum_e m_e[e,:]; t_next = ca*p + cb*t_prev; acc += theta[k]*t_next
__global__ void k_phaseB(const uint4* __restrict__ m_e,     // bf16
                         const float* __restrict__ dv_is,
                         const int* __restrict__ node_ptr,
                         const int* __restrict__ node_edge,
                         uint4* __restrict__ tio,            // bf16 state
                         float* __restrict__ acc,
                         const float* __restrict__ theta, int k,
                         float ca, float cb) {
    int sub  = threadIdx.x >> 4;
    int lane = threadIdx.x & 15;
    int v = blockIdx.x * 16 + sub;
    int s = node_ptr[v], t = node_ptr[v + 1];
    float s0=0.f,s1=0.f,s2=0.f,s3=0.f,s4=0.f,s5=0.f,s6=0.f,s7=0.f;
    int j = s;
    for (; j + 1 < t; j += 2) {
        int e0 = node_edge[j];
        int e1 = node_edge[j + 1];
        uint4 q0 = m_e[e0 * R16 + lane];
        uint4 q1 = m_e[e1 * R16 + lane];
        s0 += blo(q0.x) + blo(q1.x); s1 += bhi(q0.x) + bhi(q1.x);
        s2 += blo(q0.y) + blo(q1.y); s3 += bhi(q0.y) + bhi(q1.y);
        s4 += blo(q0.z) + blo(q1.z); s5 += bhi(q0.z) + bhi(q1.z);
        s6 += blo(q0.w) + blo(q1.w); s7 += bhi(q0.w) + bhi(q1.w);
    }
    if (j < t) {
        int e0 = node_edge[j];
        uint4 q0 = m_e[e0 * R16 + lane];
        s0 += blo(q0.x); s1 += bhi(q0.x);
        s2 += blo(q0.y); s3 += bhi(q0.y);
        s4 += blo(q0.z); s5 += bhi(q0.z);
        s6 += blo(q0.w); s7 += bhi(q0.w);
    }
    float sc = dv_is[v] * ca;
    float th = theta[k];
    int idx = v * R16 + lane;
    uint4 tp = tio[idx];
    float t0 = sc * s0 + cb * blo(tp.x);
    float t1 = sc * s1 + cb * bhi(tp.x);
    float t2 = sc * s2 + cb * blo(tp.y);
    float t3 = sc * s3 + cb * bhi(tp.y);
    float t4 = sc * s4 + cb * blo(tp.z);
    float t5 = sc * s5 + cb * bhi(tp.z);
    float t6 = sc * s6 + cb * blo(tp.w);
    float t7 = sc * s7 + cb * bhi(tp.w);
    uint4 tn;
    tn.x = pack2(t0, t1); tn.y = pack2(t2, t3);
    tn.z = pack2(t4, t5); tn.w = pack2(t6, t7);
    tio[idx] = tn;
    float4* acc4 = (float4*)acc;
    int ai = v * 32 + lane * 2;
    float4 a = acc4[ai];
    a.x += th * t0; a.y += th * t1; a.z += th * t2; a.w += th * t3;
    acc4[ai] = a;
    float4 b = acc4[ai + 1];
    b.x += th * t4; b.y += th * t5; b.z += th * t6; b.w += th * t7;
    acc4[ai + 1] = b;
}

// ---------------------------------------------------------------- GEMM: out = relu(acc @ W^T + b)
// 64x64 tile, BK=64 x2. LDS [row][k4] pad-17. Interleaved micro-tile
// (rows ty+16i, cols tx+16j): conflict-free (r5-verified: out of top-5).
__global__ __launch_bounds__(256) void k_gemm(const float* __restrict__ A,
                                              const float* __restrict__ W,
                                              const float* __restrict__ bias,
                                              float* __restrict__ out) {
    __shared__ __align__(16) float4 As4[64 * 17];
    __shared__ __align__(16) float4 Ws4[64 * 17];
    int m0 = blockIdx.y * 64;
    int h0 = blockIdx.x * 64;
    int tid = (int)threadIdx.x;
    int ty = tid >> 4, tx = tid & 15;
    float cacc[4][4];
#pragma unroll
    for (int i = 0; i < 4; ++i)
#pragma unroll
        for (int j = 0; j < 4; ++j) cacc[i][j] = 0.f;

    const float4* A4 = (const float4*)A;
    const float4* W4 = (const float4*)W;

    for (int kb = 0; kb < 2; ++kb) {
#pragma unroll
        for (int i = 0; i < 4; ++i) {
            int c   = tid + i * 256;
            int row = c >> 4;
            int k4  = c & 15;
            int gr = m0 + row;
            As4[row * 17 + k4] = (gr < N_NODES) ? A4[gr * F4 + kb * 16 + k4]
                                                : make_float4(0.f, 0.f, 0.f, 0.f);
            Ws4[row * 17 + k4] = W4[(h0 + row) * F4 + kb * 16 + k4];
        }
        __syncthreads();
#pragma unroll
        for (int k4 = 0; k4 < 16; ++k4) {
            float4 a[4], w[4];
#pragma unroll
            for (int i = 0; i < 4; ++i) a[i] = As4[(ty + 16 * i) * 17 + k4];
#pragma unroll
            for (int j = 0; j < 4; ++j) w[j] = Ws4[(tx + 16 * j) * 17 + k4];
#pragma unroll
            for (int i = 0; i < 4; ++i)
#pragma unroll
                for (int j = 0; j < 4; ++j) {
                    cacc[i][j] += a[i].x * w[j].x;
                    cacc[i][j] += a[i].y * w[j].y;
                    cacc[i][j] += a[i].z * w[j].z;
                    cacc[i][j] += a[i].w * w[j].w;
                }
        }
        __syncthreads();
    }

    float bb[4];
#pragma unroll
    for (int j = 0; j < 4; ++j) bb[j] = bias[h0 + tx + 16 * j];
#pragma unroll
    for (int i = 0; i < 4; ++i) {
        int r = m0 + ty + 16 * i;
        if (r < N_NODES) {
#pragma unroll
            for (int j = 0; j < 4; ++j) {
                out[(size_t)r * HID + h0 + tx + 16 * j] =
                    fmaxf(cacc[i][j] + bb[j], 0.f);
            }
        }
    }
}

// ----------------------------------------------------------------
extern "C" void kernel_launch(void* const* d_in, const int* in_sizes, int n_in,
                              void* d_out, int out_size, void* d_ws, size_t ws_size,
                              hipStream_t stream) {
    const float* x     = (const float*)d_in[0];
    const int*   hidx  = (const int*)d_in[1];    // int32, [2, NNZ] row-major
    const float* ew    = (const float*)d_in[2];
    const float* theta = (const float*)d_in[3];
    const float* w1    = (const float*)d_in[4];
    const float* b1    = (const float*)d_in[5];
    float*       out   = (float*)d_out;
    int kp1 = in_sizes[3];  // K+1 (= 11)

    // ---- scratch carved out of d_out (free until the final GEMM) ----
    char* ob = (char*)d_out;
    size_t oo = 0;
    auto oalloc = [&](size_t bytes) -> void* {
        void* p = ob + oo;
        oo = (oo + bytes + 255) & ~(size_t)255;
        return p;
    };
    uint4* bufA      = (uint4*)oalloc((size_t)N_NODES * F_IN * 2);   // bf16 12.8MB
    uint4* bufB      = (uint4*)oalloc((size_t)N_NODES * F_IN * 2);   // bf16 12.8MB
    uint4* m_e       = (uint4*)oalloc((size_t)N_EDGES * F_IN * 2);   // bf16 2.56MB
    int*   edge_node = (int*)oalloc((size_t)NNZ * 4);
    int*   node_edge = (int*)oalloc((size_t)NNZ * 4);
    int*   rank_e    = (int*)oalloc((size_t)NNZ * 4);
    int*   rank_v    = (int*)oalloc((size_t)NNZ * 4);
    int*   d_e_cnt16 = (int*)oalloc((size_t)N_EDGES * 16 * 4);       // 640KB
    int*   n_cnt16   = (int*)oalloc((size_t)N_NODES * 16 * 4);       // 3.2MB
    // total ~45MB < 102.4MB

    // ---- d_ws (~26MB, within r3's proven envelope) ----
    char* ws = (char*)d_ws;
    size_t off = 0;
    auto alloc = [&](size_t bytes) -> void* {
        void* p = ws + off;
        off = (off + bytes + 255) & ~(size_t)255;
        return p;
    };
    float* accv     = (float*)alloc((size_t)N_NODES * F_IN * 4);
    float* dv_is    = (float*)alloc((size_t)N_NODES * 4);
    float* de_w     = (float*)alloc((size_t)N_EDGES * 4);
    int*   edge_ptr = (int*)alloc((size_t)(N_EDGES + 1) * 4);
    int*   node_ptr = (int*)alloc((size_t)(N_NODES + 1) * 4);
    int*   part_e   = (int*)alloc(64 * 4);
    int*   part_n   = (int*)alloc(64 * 4);

    const int NB_E = (N_EDGES + 1023) / 1024;   // 10
    const int NB_N = (N_NODES + 1023) / 1024;   // 49

    k_zero2<<<(N_NODES * 16 + 255) / 256, 256, 0, stream>>>(d_e_cnt16, n_cnt16);
    k_degrees<<<(NNZ + 255) / 256, 256, 0, stream>>>(hidx, d_e_cnt16, n_cnt16, rank_e, rank_v);

    k_scan_blk<<<NB_E, 1024, 0, stream>>>(d_e_cnt16, N_EDGES, 16, edge_ptr, part_e);
    k_scan_top<<<1, 64, 0, stream>>>(part_e, NB_E, edge_ptr + N_EDGES);
    k_scan_add<<<NB_E, 1024, 0, stream>>>(edge_ptr, N_EDGES, part_e);

    k_scan_blk<<<NB_N, 1024, 0, stream>>>(n_cnt16, N_NODES, 16, node_ptr, part_n);
    k_scan_top<<<1, 64, 0, stream>>>(part_n, NB_N, node_ptr + N_NODES);
    k_scan_add<<<NB_N, 1024, 0, stream>>>(node_ptr, N_NODES, part_n);

    k_fill<<<(NNZ + 255) / 256, 256, 0, stream>>>(hidx, edge_ptr, node_ptr,
                                                  rank_e, rank_v, edge_node, node_edge);
    k_norms2<<<(N_NODES + 255) / 256, 256, 0, stream>>>(ew, edge_ptr, node_ptr,
                                                        node_edge, dv_is, de_w);
    k_init<<<(N_NODES * R16 + 255) / 256, 256, 0, stream>>>(x, theta, bufA, accv);

    for (int k = 1; k < kp1; ++k) {
        const uint4* tin = (k & 1) ? bufA : bufB;   // T_{k-1}
        uint4*       tio = (k & 1) ? bufB : bufA;   // T_{k-2} -> T_k
        float ca = (k == 1) ? -1.f : -2.f;
        float cb = (k == 1) ? 0.f : -1.f;
        k_phaseA<<<N_EDGES / 16, 256, 0, stream>>>(tin, dv_is, de_w, edge_ptr, edge_node, m_e);
        k_phaseB<<<N_NODES / 16, 256, 0, stream>>>(m_e, dv_is, node_ptr, node_edge,
                                                   tio, accv, theta, k, ca, cb);
    }

    dim3 ggrid(HID / 64, (N_NODES + 63) / 64);
    k_gemm<<<ggrid, 256, 0, stream>>>(accv, w1, b1, out);
}

// Round 7
// 827.601 us; speedup vs baseline: 2.1490x; 1.2424x over previous
//
#include <hip/hip_runtime.h>

// HypergraphGuidedChebNet on MI355X.
//   1. zero padded counters  2. degrees (padded atomics + rank capture)
//   3. scans  4. fill CSR (atomic-free)  5. norms2  6. init
//   7. 10x [phaseA edge-gather, phaseB node-gather + Cheb + acc]
//      (bf16 rows, 2 member-streams x 16 lanes per row-task, shfl_xor combine)
//   8. bf16 MFMA GEMM (fp32->bf16 cast in staging), XCD-banded swizzle
//
// Round 7 theory:
//   - gemm was VALU-capped at 39% fp32 peak (VALUBusy 90%) -> MFMA bf16.
//     FETCH 100MB (= 4x A) from XCD round-robin -> m-band swizzle (id&7 owns
//     a contiguous 98-tile m band; 3.2MB fp32 band < 4MB XCD L2).
//   - phases ~800us at ~4.5TB/s effective gather = latency/TLP-bound.
//     2 streams/edge doubles waves/CU (9.8 -> 19.5), unroll-2/stream keeps
//     4 outstanding 256B row-gathers per task.

#define N_NODES 50000
#define N_EDGES 10000
#define NNZ     800000
#define F_IN    128
#define HID     512
#define F4      (F_IN / 4)
#define R16     16           // 16 uint4 per bf16 row

typedef __attribute__((ext_vector_type(8))) short bf16x8;
typedef __attribute__((ext_vector_type(4))) float f32x4;

static __device__ __forceinline__ unsigned short f2bf(float f) {
    union { float f; unsigned u; } c; c.f = f;
    unsigned u = c.u;
    unsigned r = (u + 0x7fffu + ((u >> 16) & 1u)) >> 16;
    return (unsigned short)r;
}
static __device__ __forceinline__ float blo(unsigned u) {
    union { unsigned u; float f; } c; c.u = u << 16; return c.f;
}
static __device__ __forceinline__ float bhi(unsigned u) {
    union { unsigned u; float f; } c; c.u = u & 0xffff0000u; return c.f;
}
static __device__ __forceinline__ unsigned pack2(float lo, float hi) {
    return (unsigned)f2bf(lo) | ((unsigned)f2bf(hi) << 16);
}

// ---------------------------------------------------------------- zero padded counters
__global__ void k_zero2(int* __restrict__ d_e_cnt16, int* __restrict__ n_cnt16) {
    int i = blockIdx.x * blockDim.x + threadIdx.x;
    if (i < N_NODES * 16) n_cnt16[i] = 0;
    if (i < N_EDGES * 16) d_e_cnt16[i] = 0;
}

// ---------------------------------------------------------------- degrees + rank capture
__global__ void k_degrees(const int* __restrict__ hidx,
                          int* __restrict__ d_e_cnt16,
                          int* __restrict__ n_cnt16,
                          int* __restrict__ rank_e,
                          int* __restrict__ rank_v) {
    int i = blockIdx.x * blockDim.x + threadIdx.x;
    if (i >= NNZ) return;
    int v = hidx[i];
    int e = hidx[NNZ + i];
    v = min(max(v, 0), N_NODES - 1);
    e = min(max(e, 0), N_EDGES - 1);
    rank_e[i] = atomicAdd(&d_e_cnt16[e << 4], 1);
    rank_v[i] = atomicAdd(&n_cnt16[v << 4], 1);
}

// ---------------------------------------------------------------- scan p1 (strided counts)
__global__ __launch_bounds__(1024) void k_scan_blk(const int* __restrict__ counts, int n,
                                                   int stride,
                                                   int* __restrict__ out,
                                                   int* __restrict__ partial) {
    __shared__ int sd[1024];
    int tid = (int)threadIdx.x;
    int i = blockIdx.x * 1024 + tid;
    int v = (i < n) ? counts[(size_t)i * stride] : 0;
    sd[tid] = v;
    __syncthreads();
    for (int off = 1; off < 1024; off <<= 1) {
        int t = (tid >= off) ? sd[tid - off] : 0;
        __syncthreads();
        sd[tid] += t;
        __syncthreads();
    }
    if (i < n) out[i] = sd[tid] - v;
    if (tid == 1023) partial[blockIdx.x] = sd[1023];
}

// ---------------------------------------------------------------- scan p2 (nb <= 64)
__global__ void k_scan_top(int* __restrict__ partial, int nb, int* __restrict__ total_out) {
    int lane = (int)threadIdx.x;
    int v = (lane < nb) ? partial[lane] : 0;
    int incl = v;
    for (int off = 1; off < 64; off <<= 1) {
        int t = __shfl_up(incl, off);
        if (lane >= off) incl += t;
    }
    if (lane < nb) partial[lane] = incl - v;
    if (lane == 63) *total_out = incl;
}

// ---------------------------------------------------------------- scan p3
__global__ __launch_bounds__(1024) void k_scan_add(int* __restrict__ out, int n,
                                                   const int* __restrict__ partial) {
    int i = blockIdx.x * 1024 + (int)threadIdx.x;
    if (i < n) out[i] += partial[blockIdx.x];
}

// ---------------------------------------------------------------- CSR fill (atomic-free)
__global__ void k_fill(const int* __restrict__ hidx,
                       const int* __restrict__ edge_ptr,
                       const int* __restrict__ node_ptr,
                       const int* __restrict__ rank_e,
                       const int* __restrict__ rank_v,
                       int* __restrict__ edge_node,
                       int* __restrict__ node_edge) {
    int i = blockIdx.x * blockDim.x + threadIdx.x;
    if (i >= NNZ) return;
    int v = hidx[i];
    int e = hidx[NNZ + i];
    v = min(max(v, 0), N_NODES - 1);
    e = min(max(e, 0), N_EDGES - 1);
    edge_node[edge_ptr[e] + rank_e[i]] = v;
    node_edge[node_ptr[v] + rank_v[i]] = e;
}

// ---------------------------------------------------------------- norms from CSR
__global__ void k_norms2(const float* __restrict__ ew,
                         const int* __restrict__ edge_ptr,
                         const int* __restrict__ node_ptr,
                         const int* __restrict__ node_edge,
                         float* __restrict__ dv_is,
                         float* __restrict__ de_w) {
    int i = blockIdx.x * blockDim.x + threadIdx.x;
    if (i < N_NODES) {
        int s = node_ptr[i], t = node_ptr[i + 1];
        float d = 0.f;
        for (int j = s; j < t; ++j) d += ew[node_edge[j]];
        dv_is[i] = (d > 0.f) ? rsqrtf(fmaxf(d, 1e-12f)) : 0.f;
    }
    if (i < N_EDGES) {
        int c = edge_ptr[i + 1] - edge_ptr[i];
        de_w[i] = ew[i] * ((c > 0) ? (1.f / (float)c) : 0.f);
    }
}

// ---------------------------------------------------------------- init
__global__ void k_init(const float* __restrict__ x,
                       const float* __restrict__ theta,
                       uint4* __restrict__ bufA,
                       float* __restrict__ acc) {
    int i = blockIdx.x * blockDim.x + threadIdx.x;
    if (i >= N_NODES * R16) return;
    float4 x0 = ((const float4*)x)[2 * i];
    float4 x1 = ((const float4*)x)[2 * i + 1];
    uint4 q;
    q.x = pack2(x0.x, x0.y); q.y = pack2(x0.z, x0.w);
    q.z = pack2(x1.x, x1.y); q.w = pack2(x1.z, x1.w);
    bufA[i] = q;
    float t0 = theta[0];
    float4 a0, a1;
    a0.x = t0 * x0.x; a0.y = t0 * x0.y; a0.z = t0 * x0.z; a0.w = t0 * x0.w;
    a1.x = t0 * x1.x; a1.y = t0 * x1.y; a1.z = t0 * x1.z; a1.w = t0 * x1.w;
    ((float4*)acc)[2 * i]     = a0;
    ((float4*)acc)[2 * i + 1] = a1;
}

// ---------------------------------------------------------------- phase A
// 8 edges/block; per edge 32 lanes = 2 member-streams x 16 feature-lanes.
__global__ void k_phaseA(const uint4* __restrict__ tin,
                         const float* __restrict__ dv_is,
                         const float* __restrict__ de_w,
                         const int* __restrict__ edge_ptr,
                         const int* __restrict__ edge_node,
                         uint4* __restrict__ m_e) {
    int g      = threadIdx.x >> 5;
    int stream = (threadIdx.x >> 4) & 1;
    int lane   = threadIdx.x & 15;
    int e = blockIdx.x * 8 + g;
    int s = edge_ptr[e], t = edge_ptr[e + 1];
    float a0=0.f,a1=0.f,a2=0.f,a3=0.f,a4=0.f,a5=0.f,a6=0.f,a7=0.f;
    int j = s + stream;
    for (; j + 2 < t; j += 4) {   // unroll-2 per stream (stride-2 members)
        int v0 = edge_node[j];
        int v1 = edge_node[j + 2];
        float w0 = dv_is[v0];
        float w1 = dv_is[v1];
        uint4 q0 = tin[v0 * R16 + lane];
        uint4 q1 = tin[v1 * R16 + lane];
        a0 += w0 * blo(q0.x); a1 += w0 * bhi(q0.x);
        a2 += w0 * blo(q0.y); a3 += w0 * bhi(q0.y);
        a4 += w0 * blo(q0.z); a5 += w0 * bhi(q0.z);
        a6 += w0 * blo(q0.w); a7 += w0 * bhi(q0.w);
        a0 += w1 * blo(q1.x); a1 += w1 * bhi(q1.x);
        a2 += w1 * blo(q1.y); a3 += w1 * bhi(q1.y);
        a4 += w1 * blo(q1.z); a5 += w1 * bhi(q1.z);
        a6 += w1 * blo(q1.w); a7 += w1 * bhi(q1.w);
    }
    if (j < t) {
        int v0 = edge_node[j];
        float w0 = dv_is[v0];
        uint4 q0 = tin[v0 * R16 + lane];
        a0 += w0 * blo(q0.x); a1 += w0 * bhi(q0.x);
        a2 += w0 * blo(q0.y); a3 += w0 * bhi(q0.y);
        a4 += w0 * blo(q0.z); a5 += w0 * bhi(q0.z);
        a6 += w0 * blo(q0.w); a7 += w0 * bhi(q0.w);
    }
    // combine the two streams (lane L <-> L^16)
    a0 += __shfl_xor(a0, 16); a1 += __shfl_xor(a1, 16);
    a2 += __shfl_xor(a2, 16); a3 += __shfl_xor(a3, 16);
    a4 += __shfl_xor(a4, 16); a5 += __shfl_xor(a5, 16);
    a6 += __shfl_xor(a6, 16); a7 += __shfl_xor(a7, 16);
    if (stream == 0) {
        float w = de_w[e];
        uint4 o;
        o.x = pack2(a0 * w, a1 * w); o.y = pack2(a2 * w, a3 * w);
        o.z = pack2(a4 * w, a5 * w); o.w = pack2(a6 * w, a7 * w);
        m_e[e * R16 + lane] = o;
    }
}

// ---------------------------------------------------------------- phase B
// 8 nodes/block; per node 32 lanes = 2 edge-streams x 16 feature-lanes.
__global__ void k_phaseB(const uint4* __restrict__ m_e,
                         const float* __restrict__ dv_is,
                         const int* __restrict__ node_ptr,
                         const int* __restrict__ node_edge,
                         uint4* __restrict__ tio,
                         float* __restrict__ acc,
                         const float* __restrict__ theta, int k,
                         float ca, float cb) {
    int g      = threadIdx.x >> 5;
    int stream = (threadIdx.x >> 4) & 1;
    int lane   = threadIdx.x & 15;
    int v = blockIdx.x * 8 + g;
    int s = node_ptr[v], t = node_ptr[v + 1];
    float s0=0.f,s1=0.f,s2=0.f,s3=0.f,s4=0.f,s5=0.f,s6=0.f,s7=0.f;
    int j = s + stream;
    for (; j + 2 < t; j += 4) {
        int e0 = node_edge[j];
        int e1 = node_edge[j + 2];
        uint4 q0 = m_e[e0 * R16 + lane];
        uint4 q1 = m_e[e1 * R16 + lane];
        s0 += blo(q0.x) + blo(q1.x); s1 += bhi(q0.x) + bhi(q1.x);
        s2 += blo(q0.y) + blo(q1.y); s3 += bhi(q0.y) + bhi(q1.y);
        s4 += blo(q0.z) + blo(q1.z); s5 += bhi(q0.z) + bhi(q1.z);
        s6 += blo(q0.w) + blo(q1.w); s7 += bhi(q0.w) + bhi(q1.w);
    }
    if (j < t) {
        int e0 = node_edge[j];
        uint4 q0 = m_e[e0 * R16 + lane];
        s0 += blo(q0.x); s1 += bhi(q0.x);
        s2 += blo(q0.y); s3 += bhi(q0.y);
        s4 += blo(q0.z); s5 += bhi(q0.z);
        s6 += blo(q0.w); s7 += bhi(q0.w);
    }
    s0 += __shfl_xor(s0, 16); s1 += __shfl_xor(s1, 16);
    s2 += __shfl_xor(s2, 16); s3 += __shfl_xor(s3, 16);
    s4 += __shfl_xor(s4, 16); s5 += __shfl_xor(s5, 16);
    s6 += __shfl_xor(s6, 16); s7 += __shfl_xor(s7, 16);
    if (stream == 0) {
        float sc = dv_is[v] * ca;
        float th = theta[k];
        int idx = v * R16 + lane;
        uint4 tp = tio[idx];
        float t0 = sc * s0 + cb * blo(tp.x);
        float t1 = sc * s1 + cb * bhi(tp.x);
        float t2 = sc * s2 + cb * blo(tp.y);
        float t3 = sc * s3 + cb * bhi(tp.y);
        float t4 = sc * s4 + cb * blo(tp.z);
        float t5 = sc * s5 + cb * bhi(tp.z);
        float t6 = sc * s6 + cb * blo(tp.w);
        float t7 = sc * s7 + cb * bhi(tp.w);
        uint4 tn;
        tn.x = pack2(t0, t1); tn.y = pack2(t2, t3);
        tn.z = pack2(t4, t5); tn.w = pack2(t6, t7);
        tio[idx] = tn;
        float4* acc4 = (float4*)acc;
        int ai = v * 32 + lane * 2;
        float4 a = acc4[ai];
        a.x += th * t0; a.y += th * t1; a.z += th * t2; a.w += th * t3;
        acc4[ai] = a;
        float4 b = acc4[ai + 1];
        b.x += th * t4; b.y += th * t5; b.z += th * t6; b.w += th * t7;
        acc4[ai + 1] = b;
    }
}

// ---------------------------------------------------------------- MFMA GEMM
// out = relu(A @ W^T + b), A=accv fp32 [M][128], W fp32 [512][128].
// Block: 256thr=4 waves, tile M=64 N=64, K=128 fully staged.
// fp32->bf16 cast during LDS staging (no extra buffers).
// LDS row = 136 shorts (272B): lane bank spread uniform -> conflict-free.
// XCD swizzle: id&7 = band; each band owns 98 contiguous m-tiles.
#define M_TILES 782
__global__ __launch_bounds__(256) void k_gemm(const float* __restrict__ A,
                                              const float* __restrict__ W,
                                              const float* __restrict__ bias,
                                              float* __restrict__ out) {
    __shared__ short Asm[64 * 136];
    __shared__ short Wsm[64 * 136];
    int id  = (int)blockIdx.x;
    int xcd = id & 7;
    int sub = id >> 3;
    int h_t = sub & 7;
    int m_i = sub >> 3;                 // 0..97
    int m_t = xcd * 98 + m_i;
    if (m_t >= M_TILES) return;
    int m0 = m_t * 64;
    int h0 = h_t * 64;
    int tid = (int)threadIdx.x;

    const float4* A4 = (const float4*)A;
    const float4* W4 = (const float4*)W;
#pragma unroll
    for (int i = 0; i < 4; ++i) {
        int c   = tid + i * 256;        // 0..1023
        int row = c >> 4;               // 0..63
        int q4  = c & 15;               // uint4 column
        int gr = m0 + row;
        float4 a0, a1;
        if (gr < N_NODES) {
            a0 = A4[(size_t)gr * 32 + q4 * 2];
            a1 = A4[(size_t)gr * 32 + q4 * 2 + 1];
        } else {
            a0 = make_float4(0.f, 0.f, 0.f, 0.f);
            a1 = a0;
        }
        uint4 pa;
        pa.x = pack2(a0.x, a0.y); pa.y = pack2(a0.z, a0.w);
        pa.z = pack2(a1.x, a1.y); pa.w = pack2(a1.z, a1.w);
        *(uint4*)&Asm[row * 136 + q4 * 8] = pa;
        float4 w0 = W4[(size_t)(h0 + row) * 32 + q4 * 2];
        float4 w1 = W4[(size_t)(h0 + row) * 32 + q4 * 2 + 1];
        uint4 pw;
        pw.x = pack2(w0.x, w0.y); pw.y = pack2(w0.z, w0.w);
        pw.z = pack2(w1.x, w1.y); pw.w = pack2(w1.z, w1.w);
        *(uint4*)&Wsm[row * 136 + q4 * 8] = pw;
    }
    __syncthreads();

    int lane = tid & 63;
    int wv   = tid >> 6;                // wave 0..3 -> m rows wv*16..+15
    int l16  = lane & 15;
    int quad = lane >> 4;

    f32x4 acc[4];
#pragma unroll
    for (int n = 0; n < 4; ++n) acc[n] = (f32x4){0.f, 0.f, 0.f, 0.f};

#pragma unroll
    for (int ks = 0; ks < 4; ++ks) {
        int k0 = ks * 32;
        // A-frag: A[m = l16][k = quad*8 + j]
        bf16x8 af = *(const bf16x8*)&Asm[(wv * 16 + l16) * 136 + k0 + quad * 8];
#pragma unroll
        for (int n = 0; n < 4; ++n) {
            bf16x8 bf = *(const bf16x8*)&Wsm[(n * 16 + l16) * 136 + k0 + quad * 8];
            acc[n] = __builtin_amdgcn_mfma_f32_16x16x32_bf16(af, bf, acc[n], 0, 0, 0);
        }
    }

    // C/D layout: col = lane&15, row = quad*4 + reg   (m89/m91-verified)
#pragma unroll
    for (int n = 0; n < 4; ++n) {
        float bb = bias[h0 + n * 16 + l16];
#pragma unroll
        for (int r = 0; r < 4; ++r) {
            int gr = m0 + wv * 16 + quad * 4 + r;
            if (gr < N_NODES)
                out[(size_t)gr * HID + h0 + n * 16 + l16] =
                    fmaxf(acc[n][r] + bb, 0.f);
        }
    }
}

// ----------------------------------------------------------------
extern "C" void kernel_launch(void* const* d_in, const int* in_sizes, int n_in,
                              void* d_out, int out_size, void* d_ws, size_t ws_size,
                              hipStream_t stream) {
    const float* x     = (const float*)d_in[0];
    const int*   hidx  = (const int*)d_in[1];    // int32, [2, NNZ] row-major
    const float* ew    = (const float*)d_in[2];
    const float* theta = (const float*)d_in[3];
    const float* w1    = (const float*)d_in[4];
    const float* b1    = (const float*)d_in[5];
    float*       out   = (float*)d_out;
    int kp1 = in_sizes[3];  // K+1 (= 11)

    // ---- scratch carved out of d_out (all dead before k_gemm's writes) ----
    char* ob = (char*)d_out;
    size_t oo = 0;
    auto oalloc = [&](size_t bytes) -> void* {
        void* p = ob + oo;
        oo = (oo + bytes + 255) & ~(size_t)255;
        return p;
    };
    uint4* bufA      = (uint4*)oalloc((size_t)N_NODES * F_IN * 2);
    uint4* bufB      = (uint4*)oalloc((size_t)N_NODES * F_IN * 2);
    uint4* m_e       = (uint4*)oalloc((size_t)N_EDGES * F_IN * 2);
    int*   edge_node = (int*)oalloc((size_t)NNZ * 4);
    int*   node_edge = (int*)oalloc((size_t)NNZ * 4);
    int*   rank_e    = (int*)oalloc((size_t)NNZ * 4);
    int*   rank_v    = (int*)oalloc((size_t)NNZ * 4);
    int*   d_e_cnt16 = (int*)oalloc((size_t)N_EDGES * 16 * 4);
    int*   n_cnt16   = (int*)oalloc((size_t)N_NODES * 16 * 4);

    // ---- d_ws (~26MB) ----
    char* ws = (char*)d_ws;
    size_t off = 0;
    auto alloc = [&](size_t bytes) -> void* {
        void* p = ws + off;
        off = (off + bytes + 255) & ~(size_t)255;
        return p;
    };
    float* accv     = (float*)alloc((size_t)N_NODES * F_IN * 4);
    float* dv_is    = (float*)alloc((size_t)N_NODES * 4);
    float* de_w     = (float*)alloc((size_t)N_EDGES * 4);
    int*   edge_ptr = (int*)alloc((size_t)(N_EDGES + 1) * 4);
    int*   node_ptr = (int*)alloc((size_t)(N_NODES + 1) * 4);
    int*   part_e   = (int*)alloc(64 * 4);
    int*   part_n   = (int*)alloc(64 * 4);

    const int NB_E = (N_EDGES + 1023) / 1024;   // 10
    const int NB_N = (N_NODES + 1023) / 1024;   // 49

    k_zero2<<<(N_NODES * 16 + 255) / 256, 256, 0, stream>>>(d_e_cnt16, n_cnt16);
    k_degrees<<<(NNZ + 255) / 256, 256, 0, stream>>>(hidx, d_e_cnt16, n_cnt16, rank_e, rank_v);

    k_scan_blk<<<NB_E, 1024, 0, stream>>>(d_e_cnt16, N_EDGES, 16, edge_ptr, part_e);
    k_scan_top<<<1, 64, 0, stream>>>(part_e, NB_E, edge_ptr + N_EDGES);
    k_scan_add<<<NB_E, 1024, 0, stream>>>(edge_ptr, N_EDGES, part_e);

    k_scan_blk<<<NB_N, 1024, 0, stream>>>(n_cnt16, N_NODES, 16, node_ptr, part_n);
    k_scan_top<<<1, 64, 0, stream>>>(part_n, NB_N, node_ptr + N_NODES);
    k_scan_add<<<NB_N, 1024, 0, stream>>>(node_ptr, N_NODES, part_n);

    k_fill<<<(NNZ + 255) / 256, 256, 0, stream>>>(hidx, edge_ptr, node_ptr,
                                                  rank_e, rank_v, edge_node, node_edge);
    k_norms2<<<(N_NODES + 255) / 256, 256, 0, stream>>>(ew, edge_ptr, node_ptr,
                                                        node_edge, dv_is, de_w);
    k_init<<<(N_NODES * R16 + 255) / 256, 256, 0, stream>>>(x, theta, bufA, accv);

    for (int k = 1; k < kp1; ++k) {
        const uint4* tin = (k & 1) ? bufA : bufB;   // T_{k-1}
        uint4*       tio = (k & 1) ? bufB : bufA;   // T_{k-2} -> T_k
        float ca = (k == 1) ? -1.f : -2.f;
        float cb = (k == 1) ? 0.f : -1.f;
        k_phaseA<<<N_EDGES / 8, 256, 0, stream>>>(tin, dv_is, de_w, edge_ptr, edge_node, m_e);
        k_phaseB<<<N_NODES / 8, 256, 0, stream>>>(m_e, dv_is, node_ptr, node_edge,
                                                  tio, accv, theta, k, ca, cb);
    }

    // 8 bands x 98 m-tiles x 8 h-tiles (2 tail tiles early-return)
    k_gemm<<<8 * 98 * 8, 256, 0, stream>>>(accv, w1, b1, out);
}